// Round 4
// baseline (350.777 us; speedup 1.0000x reference)
//
#include <hip/hip_runtime.h>

// SNN: 3-layer LIF, B=256, T=32, H=1024, IN=2312, OUT=10.
// Round-5: GEMM1 fp16 2-plane split, 3 passes (absmax 0.0).
// Round-6 FAILED: BM128xBN256 -> grid 256 = 1 block/CU -> barrier-serialized
//   (VALUBusy 15%, 60% stall). Lesson: need >=2 independent blocks/CU.
// Round-7: B never touches LDS. Weight planes are pre-split into
//   MFMA-B-fragment order (1KB per (n16,k32) frag: elem(lane,e) =
//   W[n16*16+(lane&15)][k32*32+(lane>>4)*8+e]), so waves load bfr with one
//   coalesced global dwordx4 from the XCD-local L2 slice (nblk = blockIdx&7
//   pins each 1.21MB B n-slice to one XCD's L2). Only A (fp32 split) keeps
//   the LDS+barrier path. BM=BN=128, 4 waves 2Mx2N of 64x64, 256 thr,
//   grid 512 = 2 blocks/CU. Per-CU floors: MFMA 138k cyc (binding),
//   LDS 85k, vmem ~130k, VALU ~95k.

#define TB 256
#define TT 32
#define TH 1024
#define TIN 2312
#define TOUT 10
#define TM (TT * TB)   // 8192 rows = (t,b)
#define NK1 74         // K-tiles of 32 for GEMM1 (2368 = 74*32)
#define NK2 32         // K-tiles for GEMM2 (1024)

typedef _Float16 f16_t;
typedef f16_t f16x8 __attribute__((ext_vector_type(8)));
typedef float floatx4 __attribute__((ext_vector_type(4)));

__device__ __forceinline__ void split2h(float v, f16_t& a, f16_t& b) {
  a = (f16_t)v;
  b = (f16_t)(v - (float)a);
}

// W (N x K) -> 2 fp16 planes in MFMA-B-fragment order:
// P[q*plane + fid*512 + lane*8 + e] =
//   split_q(W[(n16*16 + (lane&15))*K + k32*32 + (lane>>4)*8 + e]),
// fid = n16*nk32 + k32, zero for k >= K. (K % 8 == 0 for both weights.)
__global__ __launch_bounds__(256) void split_w_frag(
    const float* __restrict__ W, f16_t* __restrict__ P, long plane,
    int K, int nk32) {
  const int fid = blockIdx.x * 4 + (threadIdx.x >> 6);
  const int lane = threadIdx.x & 63;
  const int n16 = fid / nk32, k32 = fid - n16 * nk32;
  const long row = n16 * 16 + (lane & 15);
  const int k0 = k32 * 32 + (lane >> 4) * 8;
  float t[8];
  if (k0 + 8 <= K) {
    float4 v0 = *(const float4*)(W + row * K + k0);
    float4 v1 = *(const float4*)(W + row * K + k0 + 4);
    t[0] = v0.x; t[1] = v0.y; t[2] = v0.z; t[3] = v0.w;
    t[4] = v1.x; t[5] = v1.y; t[6] = v1.z; t[7] = v1.w;
  } else {
    #pragma unroll
    for (int e = 0; e < 8; ++e) t[e] = 0.f;
  }
  f16x8 h0, h1;
  #pragma unroll
  for (int e = 0; e < 8; ++e) {
    f16_t a, b;
    split2h(t[e], a, b);
    h0[e] = a; h1[e] = b;
  }
  const long o = (long)fid * 512 + lane * 8;
  *(f16x8*)(P + o) = h0;
  *(f16x8*)(P + plane + o) = h1;
}

// GEMM1: 3 fp16 passes of A(x fp32, split in-kernel via LDS) x B(W1 frag
// planes, direct from global/L2). A row elem off = (r>>8)*sT + (r&255)*sB.
// BM=BN=128, 4 waves 2Mx2N (64x64/wave); blockIdx.x = m*8 + n (n = XCD).
__global__ __launch_bounds__(256, 2) void snn_gemm1(
    const float* __restrict__ Af, long sT, long sB,
    const f16_t* __restrict__ Bf, long planeB, int nk32, int K,
    const float* __restrict__ bias, float* __restrict__ C, int N) {
  constexpr int LDW = 36;  // 32 + 4 pad
  __shared__ f16_t As[2][128 * LDW];

  const int tid = threadIdx.x;
  const int wave = tid >> 6, lane = tid & 63;
  const int quad = lane >> 4, l16 = lane & 15;
  const int wm = (wave & 1) * 64, wn = (wave >> 1) * 64;
  const int mblk = blockIdx.x >> 3, nblk = blockIdx.x & 7;
  const long m0 = (long)mblk * 128, n0 = (long)nblk * 128;

  floatx4 acc[4][4];
  #pragma unroll
  for (int i = 0; i < 4; ++i)
    #pragma unroll
    for (int j = 0; j < 4; ++j) acc[i][j] = (floatx4){0.f, 0.f, 0.f, 0.f};

  const int cr = tid >> 1;        // A-stage row 0..127
  const int cs = (tid & 1) * 16;  // A-stage k offset 0/16
  float4 xv[4];

  // wave's B fragment base: n16 = (n0+wn)/16 + j, addr (fid*512 + lane*8)
  const f16_t* Bw = Bf + (((n0 + wn) >> 4) * (long)nk32) * 512 + lane * 8;

  auto prefetchA = [&](int kb) {
    const long rA = m0 + cr;
    const int k0 = kb + cs;
    const float* xr = Af + (rA >> 8) * sT + (rA & 255) * sB + k0;
    #pragma unroll
    for (int u = 0; u < 4; ++u)
      xv[u] = (k0 + u * 4 < K) ? *(const float4*)(xr + u * 4)
                               : float4{0.f, 0.f, 0.f, 0.f};
  };

  auto commitA = [&]() {
    const int off = cr * LDW + cs;
    #pragma unroll
    for (int h = 0; h < 2; ++h) {
      float t[8] = {xv[2 * h].x,     xv[2 * h].y,     xv[2 * h].z,
                    xv[2 * h].w,     xv[2 * h + 1].x, xv[2 * h + 1].y,
                    xv[2 * h + 1].z, xv[2 * h + 1].w};
      f16x8 a8, b8;
      #pragma unroll
      for (int e = 0; e < 8; ++e) {
        f16_t a, b;
        split2h(t[e], a, b);
        a8[e] = a; b8[e] = b;
      }
      *(f16x8*)(&As[0][off + h * 8]) = a8;
      *(f16x8*)(&As[1][off + h * 8]) = b8;
    }
  };

  auto loadB = [&](int k32, f16x8 (&bf)[2][4]) {
    #pragma unroll
    for (int q = 0; q < 2; ++q)
      #pragma unroll
      for (int j = 0; j < 4; ++j)
        bf[q][j] = *(const f16x8*)(Bw + q * planeB +
                                   ((long)j * nk32 + k32) * 512);
  };

  f16x8 b0[2][4], b1[2][4];
  prefetchA(0);
  loadB(0, b0);

  auto body = [&](int kt, f16x8 (&bc)[2][4], f16x8 (&bn)[2][4]) {
    __syncthreads();   // prior tile's afr reads done
    commitA();
    prefetchA(kt + 1 < nk32 ? (kt + 1) * 32 : 0);   // harmless reload at end
    __syncthreads();   // A staging visible
    loadB(kt + 1 < nk32 ? kt + 1 : 0, bn);  // next B frags: latency under MFMA

    f16x8 afr[2][4];
    #pragma unroll
    for (int pa = 0; pa < 2; ++pa)
      #pragma unroll
      for (int i = 0; i < 4; ++i)
        afr[pa][i] =
            *(const f16x8*)(&As[pa][(wm + i * 16 + l16) * LDW + quad * 8]);

    #pragma unroll
    for (int pb = 0; pb < 2; ++pb) {
      const int pamax = 1 - pb;  // passes (0,0),(1,0),(0,1)
      #pragma unroll
      for (int pa = 0; pa < 2; ++pa) {
        if (pa > pamax) break;
        #pragma unroll
        for (int i = 0; i < 4; ++i)
          #pragma unroll
          for (int j = 0; j < 4; ++j)
            acc[i][j] = __builtin_amdgcn_mfma_f32_16x16x32_f16(
                afr[pa][i], bc[pb][j], acc[i][j], 0, 0, 0);
      }
    }
  };

  for (int kt = 0; kt < nk32; kt += 2) {  // nk32 even: 74
    body(kt, b0, b1);
    body(kt + 1, b1, b0);
  }

  // epilogue: C/D layout col=lane&15, row=quad*4+reg (dtype-independent)
  #pragma unroll
  for (int j = 0; j < 4; ++j) {
    const long col = n0 + wn + j * 16 + l16;
    const float bvv = bias[col];
    #pragma unroll
    for (int i = 0; i < 4; ++i) {
      const long row0 = m0 + wm + i * 16 + quad * 4;
      #pragma unroll
      for (int g = 0; g < 4; ++g)
        C[(row0 + g) * (long)N + col] = acc[i][j][g] + bvv;
    }
  }
}

// GEMM2: A = spikes (fp16 exact, 1 plane via LDS), B = W2 frag planes
// direct from global, 2 passes (a*b0 + a*b1 = a*(b0+b1): nothing dropped).
__global__ __launch_bounds__(256, 2) void snn_gemm2(
    const f16_t* __restrict__ Ab, long sT, long sB,
    const f16_t* __restrict__ Bf, long planeB, int nk32,
    const float* __restrict__ bias, float* __restrict__ C, int N) {
  constexpr int LDW = 36;
  __shared__ f16_t As[128 * LDW];

  const int tid = threadIdx.x;
  const int wave = tid >> 6, lane = tid & 63;
  const int quad = lane >> 4, l16 = lane & 15;
  const int wm = (wave & 1) * 64, wn = (wave >> 1) * 64;
  const int mblk = blockIdx.x >> 3, nblk = blockIdx.x & 7;
  const long m0 = (long)mblk * 128, n0 = (long)nblk * 128;

  floatx4 acc[4][4];
  #pragma unroll
  for (int i = 0; i < 4; ++i)
    #pragma unroll
    for (int j = 0; j < 4; ++j) acc[i][j] = (floatx4){0.f, 0.f, 0.f, 0.f};

  const int cr = tid >> 1;
  const int cs = (tid & 1) * 16;
  f16x8 av[2];

  const f16_t* Bw = Bf + (((n0 + wn) >> 4) * (long)nk32) * 512 + lane * 8;

  auto prefetchA = [&](int kb) {
    const long rA = m0 + cr;
    const f16_t* ar = Ab + (rA >> 8) * sT + (rA & 255) * sB + kb + cs;
    av[0] = *(const f16x8*)ar;
    av[1] = *(const f16x8*)(ar + 8);
  };

  auto commitA = [&]() {
    const int off = cr * LDW + cs;
    *(f16x8*)(&As[off]) = av[0];
    *(f16x8*)(&As[off + 8]) = av[1];
  };

  auto loadB = [&](int k32, f16x8 (&bf)[2][4]) {
    #pragma unroll
    for (int q = 0; q < 2; ++q)
      #pragma unroll
      for (int j = 0; j < 4; ++j)
        bf[q][j] = *(const f16x8*)(Bw + q * planeB +
                                   ((long)j * nk32 + k32) * 512);
  };

  f16x8 b0[2][4], b1[2][4];
  prefetchA(0);
  loadB(0, b0);

  auto body = [&](int kt, f16x8 (&bc)[2][4], f16x8 (&bn)[2][4]) {
    __syncthreads();
    commitA();
    prefetchA(kt + 1 < nk32 ? (kt + 1) * 32 : 0);
    __syncthreads();
    loadB(kt + 1 < nk32 ? kt + 1 : 0, bn);

    f16x8 afr[4];
    #pragma unroll
    for (int i = 0; i < 4; ++i)
      afr[i] = *(const f16x8*)(&As[(wm + i * 16 + l16) * LDW + quad * 8]);

    #pragma unroll
    for (int pb = 0; pb < 2; ++pb)
      #pragma unroll
      for (int i = 0; i < 4; ++i)
        #pragma unroll
        for (int j = 0; j < 4; ++j)
          acc[i][j] = __builtin_amdgcn_mfma_f32_16x16x32_f16(
              afr[i], bc[pb][j], acc[i][j], 0, 0, 0);
  };

  for (int kt = 0; kt < nk32; kt += 2) {  // nk32 = 32, even
    body(kt, b0, b1);
    body(kt + 1, b1, b0);
  }

  #pragma unroll
  for (int j = 0; j < 4; ++j) {
    const long col = n0 + wn + j * 16 + l16;
    const float bvv = bias[col];
    #pragma unroll
    for (int i = 0; i < 4; ++i) {
      const long row0 = m0 + wm + i * 16 + quad * 4;
      #pragma unroll
      for (int g = 0; g < 4; ++g)
        C[(row0 + g) * (long)N + col] = acc[i][j][g] + bvv;
    }
  }
}

// LIF scan, fp32 in -> fp16 spikes out (spikes {0,1} exact in fp16).
__global__ __launch_bounds__(256) void lif_scan_f16(const float* __restrict__ I,
                                                    f16_t* __restrict__ S) {
  int idx = blockIdx.x * 256 + threadIdx.x;
  float v = 0.f, cur = 0.f;
  #pragma unroll
  for (int t = 0; t < TT; ++t) {
    float inp = I[(long)t * (TB * TH) + idx];
    float vd = fmaf(0.05f, cur - v, v);
    float id = cur - 0.2f * cur;
    float s = (vd > 1.0f) ? 1.0f : 0.f;
    v = (1.0f - s) * vd;
    cur = id + inp;
    S[(long)t * (TB * TH) + idx] = (f16_t)s;
  }
}

// GEMM3: one wave per row; I3[r][o] = S2[r][:] . Wout[o][:] + bout[o]
__global__ __launch_bounds__(256) void gemm3_kernel(
    const f16_t* __restrict__ S2, const float* __restrict__ Wout,
    const float* __restrict__ bout, float* __restrict__ I3) {
  int wv = (blockIdx.x * blockDim.x + threadIdx.x) >> 6;
  int lane = threadIdx.x & 63;
  if (wv >= TM) return;
  const f16_t* srow = S2 + (long)wv * TH;
  float acc[TOUT];
  #pragma unroll
  for (int o = 0; o < TOUT; ++o) acc[o] = 0.f;
  for (int k = lane; k < TH; k += 64) {
    float s = (float)srow[k];
    #pragma unroll
    for (int o = 0; o < TOUT; ++o) acc[o] = fmaf(s, Wout[o * TH + k], acc[o]);
  }
  #pragma unroll
  for (int off = 32; off > 0; off >>= 1)
    #pragma unroll
    for (int o = 0; o < TOUT; ++o) acc[o] += __shfl_down(acc[o], off, 64);
  if (lane == 0) {
    #pragma unroll
    for (int o = 0; o < TOUT; ++o) I3[(long)wv * TOUT + o] = acc[o] + bout[o];
  }
}

__global__ __launch_bounds__(256) void scan_out(const float* __restrict__ I3,
                                                float* __restrict__ out) {
  int idx = blockIdx.x * blockDim.x + threadIdx.x;
  if (idx >= TB * TOUT) return;
  float v = 0.f, cur = 0.f, cnt = 0.f;
  #pragma unroll
  for (int t = 0; t < TT; ++t) {
    float inp = I3[(long)t * (TB * TOUT) + idx];
    float vd = fmaf(0.05f, cur - v, v);
    float id = cur - 0.2f * cur;
    float s = (vd > 1.0f) ? 1.0f : 0.f;
    v = (1.0f - s) * vd;
    cur = id + inp;
    cnt += s;
  }
  out[idx] = cnt;
}

extern "C" void kernel_launch(void* const* d_in, const int* in_sizes, int n_in,
                              void* d_out, int out_size, void* d_ws,
                              size_t ws_size, hipStream_t stream) {
  const float* x    = (const float*)d_in[0];  // (256,32,2312)
  const float* W1   = (const float*)d_in[1];  // (1024,2312)
  const float* b1   = (const float*)d_in[2];
  const float* W2   = (const float*)d_in[3];  // (1024,1024)
  const float* b2   = (const float*)d_in[4];
  const float* Wout = (const float*)d_in[5];  // (10,1024)
  const float* bout = (const float*)d_in[6];

  // Fragment-plane sizes (elements): W1 64 n16 x 74 k32 x 512 = 2,424,832;
  // W2 64 x 32 x 512 = 1,048,576.
  const long PL1 = 64L * NK1 * 512;
  const long PL2 = 64L * NK2 * 512;

  // ws layout (bytes):
  //   [0, 16.78M)      : W1p (2 planes, 9.70M) + W2p (2 planes, 4.19M) --
  //                      dead after GEMM2; S2 (fp16, 16.78M) ALIASES this
  //                      region (stream-sequential safe; rebuilt each call).
  //   [16.78M, 50.33M) : bufI (fp32, 33.55M)
  //   [50.33M, 67.11M) : S1 (fp16, 16.78M)
  //   [67.11M, 67.44M) : buf3 (fp32, 0.33M)
  char* base = (char*)d_ws;
  const long S2_BYTES = (long)TM * TH * 2;  // 16,777,216
  f16_t* W1p  = (f16_t*)base;
  f16_t* W2p  = (f16_t*)(base + 2 * PL1 * 2);  // after 9,699,328 B
  float* bufI = (float*)(base + S2_BYTES);
  f16_t* S1   = (f16_t*)(base + S2_BYTES + (long)TM * TH * 4);
  float* buf3 = (float*)(base + S2_BYTES + (long)TM * TH * 4 + (long)TM * TH * 2);
  f16_t* S2   = (f16_t*)base;

  split_w_frag<<<64 * NK1 / 4, 256, 0, stream>>>(W1, W1p, PL1, TIN, NK1);
  split_w_frag<<<64 * NK2 / 4, 256, 0, stream>>>(W2, W2p, PL2, TH, NK2);

  // GEMM1: row r=(t,b): x offset = t*2312 + b*(32*2312)
  snn_gemm1<<<512, 256, 0, stream>>>(x, (long)TIN, (long)TT * TIN, W1p, PL1,
                                     NK1, TIN, b1, bufI, TH);

  lif_scan_f16<<<(TB * TH) / 256, 256, 0, stream>>>(bufI, S1);

  // GEMM2: S1 row-major [8192][1024]: sT=256*1024, sB=1024
  snn_gemm2<<<512, 256, 0, stream>>>(S1, (long)TB * TH, (long)TH, W2p, PL2,
                                     NK2, b2, bufI, TH);

  lif_scan_f16<<<(TB * TH) / 256, 256, 0, stream>>>(bufI, S2);

  gemm3_kernel<<<(TM * 64) / 256, 256, 0, stream>>>(S2, Wout, bout, buf3);

  scan_out<<<(TB * TOUT + 255) / 256, 256, 0, stream>>>(buf3, (float*)d_out);
}